// Round 9
// baseline (656.437 us; speedup 1.0000x reference)
//
#include <hip/hip_runtime.h>
#include <math.h>

#define NN 50000
#define NE 1600000
#define AVG_DEG_LOG 3.4965075614664802f
#define NBIN 196            // (NN+255)/256
#define CHUNK 4096
#define NCHUNK 391          // (NE+CHUNK-1)/CHUNK

typedef float f4v __attribute__((ext_vector_type(4)));
typedef _Float16 h8v __attribute__((ext_vector_type(8)));

__device__ __forceinline__ float lrelu(float x){ return x > 0.f ? x : 0.2f*x; }
__device__ __forceinline__ float relu(float x){ return x > 0.f ? x : 0.f; }

// coarse entry (int2): x = other_node, y = local8<<24 | w_q19
__device__ __forceinline__ unsigned quant_w(float w){
    unsigned wq = (unsigned)(w * 524288.f);
    return wq > 524287u ? 524287u : wq;
}
// compact 4-byte adjacency entry: node16 | wq16<<16
__device__ __forceinline__ int cent_node(int e){ return e & 0xFFFF; }
__device__ __forceinline__ float cent_w(int e){
    return ((float)(((unsigned)e >> 16) & 0xFFFFu) + 0.5f) * (1.0f/65536.0f);
}
// order-preserving float<->uint encoding (for LDS atomicMax on floats)
__device__ __forceinline__ unsigned fenc(float f){
    unsigned b = __float_as_uint(f);
    return (b & 0x80000000u) ? ~b : (b | 0x80000000u);
}
__device__ __forceinline__ float fdec(unsigned u){
    unsigned b = (u & 0x80000000u) ? (u & 0x7FFFFFFFu) : ~u;
    return __uint_as_float(b);
}

// ================= two-level counting sort (no global atomics) =================

__global__ __launch_bounds__(256) void k_hist(const int* __restrict__ src, const int* __restrict__ dst,
                                              int* __restrict__ histD, int* __restrict__ histS){
    __shared__ int hd[NBIN], hs[NBIN];
    for (int t=threadIdx.x; t<NBIN; t+=256){ hd[t]=0; hs[t]=0; }
    __syncthreads();
    int chunk = blockIdx.x;
    int e0 = chunk*CHUNK, e1 = min(e0+CHUNK, NE);
    for (int e=e0+threadIdx.x; e<e1; e+=256){
        atomicAdd(&hd[dst[e]>>8], 1);
        atomicAdd(&hs[src[e]>>8], 1);
    }
    __syncthreads();
    for (int t=threadIdx.x; t<NBIN; t+=256){
        histD[t*NCHUNK+chunk] = hd[t];
        histS[t*NCHUNK+chunk] = hs[t];
    }
}

// stage 1: per-bin totals (grid = 2*NBIN)
__global__ __launch_bounds__(256) void k_binsum(const int* __restrict__ histD, const int* __restrict__ histS,
                                                int* __restrict__ binTotal){
    __shared__ int wsum[4];
    int dir = blockIdx.x / NBIN, bin = blockIdx.x % NBIN;
    const int* hist = dir ? histS : histD;
    int s = 0;
    for (int t=threadIdx.x; t<NCHUNK; t+=256) s += hist[bin*NCHUNK + t];
    #pragma unroll
    for (int st=32; st>=1; st>>=1) s += __shfl_xor(s, st);
    if ((threadIdx.x & 63) == 0) wsum[threadIdx.x>>6] = s;
    __syncthreads();
    if (threadIdx.x == 0) binTotal[dir*NBIN + bin] = wsum[0]+wsum[1]+wsum[2]+wsum[3];
}

// stage 2 (fused): binStart from binTotal prefix + per-bin chunk prefix (grid = 2*NBIN)
__global__ __launch_bounds__(256) void k_chunkpfx(const int* __restrict__ histD, const int* __restrict__ histS,
                                                  const int* __restrict__ binTotal,
                                                  int* __restrict__ binStartD, int* __restrict__ binStartS,
                                                  int* __restrict__ baseD, int* __restrict__ baseS){
    __shared__ int wsums[4];
    __shared__ int sbase;
    int dir = blockIdx.x / NBIN, bin = blockIdx.x % NBIN;
    const int* hist = dir ? histS : histD;
    int* binStart = dir ? binStartS : binStartD;
    int* base = dir ? baseS : baseD;
    int tid = threadIdx.x, lane = tid & 63, wv = tid >> 6;
    // binStart[bin] = sum of binTotal[dir][k] for k < bin
    {
        int s = 0;
        for (int k = tid; k < bin; k += 256) s += binTotal[dir*NBIN + k];
        #pragma unroll
        for (int st=32; st>=1; st>>=1) s += __shfl_xor(s, st);
        if (lane == 0) wsums[wv] = s;
        __syncthreads();
        if (tid == 0){
            sbase = wsums[0]+wsums[1]+wsums[2]+wsums[3];
            binStart[bin] = sbase;
            if (bin == 0) binStart[NBIN] = NE;
        }
        __syncthreads();
    }
    int bS = sbase;
    __syncthreads();
    // per-bin exclusive prefix over its NCHUNK chunk counts
    int i0 = tid*2, i1 = tid*2+1;
    int a = (i0 < NCHUNK) ? hist[bin*NCHUNK + i0] : 0;
    int b = (i1 < NCHUNK) ? hist[bin*NCHUNK + i1] : 0;
    int v = a + b;
    int sc = v;
    for (int d = 1; d < 64; d <<= 1){
        int t = __shfl_up(sc, d, 64);
        if (lane >= d) sc += t;
    }
    if (lane == 63) wsums[wv] = sc;
    __syncthreads();
    int woff = 0;
    #pragma unroll
    for (int k = 0; k < 4; ++k) woff += (k < wv) ? wsums[k] : 0;
    int excl = bS + woff + sc - v;
    if (i0 < NCHUNK) base[bin*NCHUNK + i0] = excl;
    if (i1 < NCHUNK) base[bin*NCHUNK + i1] = excl + a;
}

__global__ __launch_bounds__(256) void k_coarse(const int* __restrict__ src, const int* __restrict__ dst,
                                                const float* __restrict__ ea,
                                                const int* __restrict__ baseD, const int* __restrict__ baseS,
                                                int2* __restrict__ cD, int2* __restrict__ cS){
    __shared__ int curd[NBIN], curs[NBIN];
    int chunk = blockIdx.x;
    for (int t=threadIdx.x; t<NBIN; t+=256){
        curd[t] = baseD[t*NCHUNK+chunk];
        curs[t] = baseS[t*NCHUNK+chunk];
    }
    __syncthreads();
    int e0 = chunk*CHUNK, e1 = min(e0+CHUNK, NE);
    for (int e=e0+threadIdx.x; e<e1; e+=256){
        int s = src[e], d = dst[e];
        unsigned wq = quant_w(ea[e]);
        int pd = atomicAdd(&curd[d>>8], 1);
        cD[pd] = make_int2(s, (int)(((unsigned)(d & 255) << 24) | wq));
        int ps = atomicAdd(&curs[s>>8], 1);
        cS[ps] = make_int2(d, (int)(((unsigned)(s & 255) << 24) | wq));
    }
}

// fine sort, dst direction: compact 4B entries out
__global__ __launch_bounds__(256) void k_fine(const int2* __restrict__ cin,
                                              const int* __restrict__ binStart,
                                              int* __restrict__ bout,
                                              int* __restrict__ cnt, int* __restrict__ off){
    __shared__ int h[256], cur[256];
    __shared__ int ws4[4];
    int bin = blockIdx.x;
    int S = binStart[bin], E = binStart[bin+1];
    h[threadIdx.x] = 0;
    __syncthreads();
    for (int i = S + threadIdx.x; i < E; i += 256){
        unsigned y = (unsigned)cin[i].y;
        atomicAdd(&h[y >> 24], 1);
    }
    __syncthreads();
    int v = h[threadIdx.x];
    int lane = threadIdx.x & 63, wv = threadIdx.x >> 6;
    int sc = v;
    for (int d = 1; d < 64; d <<= 1){
        int t = __shfl_up(sc, d, 64);
        if (lane >= d) sc += t;
    }
    if (lane == 63) ws4[wv] = sc;
    __syncthreads();
    int woff = 0;
    #pragma unroll
    for (int k = 0; k < 4; ++k) woff += (k < wv) ? ws4[k] : 0;
    int excl = woff + sc - v;
    cur[threadIdx.x] = S + excl;
    int node = (bin << 8) + threadIdx.x;
    if (node < NN){ cnt[node] = v; off[node] = S + excl; }
    __syncthreads();
    for (int i = S + threadIdx.x; i < E; i += 256){
        int2 ent = cin[i];
        unsigned y = (unsigned)ent.y;
        int local = y >> 24;
        int pos = atomicAdd(&cur[local], 1);
        unsigned wq16 = (y & 0x7FFFFu) >> 3;
        bout[pos] = (int)(((unsigned)ent.x & 0xFFFFu) | (wq16 << 16));
    }
}

// ================= fallback CSR path (atomic scatter) =================

__global__ void k_zero(int* cnt_d, int* cnt_s){
    int i = blockIdx.x*blockDim.x + threadIdx.x;
    if (i < NN){ cnt_d[i]=0; cnt_s[i]=0; }
}

__global__ void k_count(const int* __restrict__ src, const int* __restrict__ dst,
                        int* cnt_d, int* cnt_s){
    int e = blockIdx.x*blockDim.x + threadIdx.x;
    if (e >= NE) return;
    atomicAdd(&cnt_d[dst[e]], 1);
    atomicAdd(&cnt_s[src[e]], 1);
}

__global__ __launch_bounds__(1024) void k_scanCSR(const int* __restrict__ cnt_d, const int* __restrict__ cnt_s,
                                                  int* off_d, int* cur_d, int* off_s, int* cur_s){
    __shared__ int wsums[16];
    __shared__ int carry_s;
    const int tid = threadIdx.x, lane = tid & 63, wv = tid >> 6;
    const int pass = blockIdx.x;
    const int* cnt = pass ? cnt_s : cnt_d;
    int* off = pass ? off_s : off_d;
    int* cur = pass ? cur_s : cur_d;
    if (tid == 0) carry_s = 0;
    __syncthreads();
    for (int base = 0; base < NN; base += 4096){
        int i0 = base + tid*4;
        int v0 = (i0+0 < NN) ? cnt[i0+0] : 0;
        int v1 = (i0+1 < NN) ? cnt[i0+1] : 0;
        int v2 = (i0+2 < NN) ? cnt[i0+2] : 0;
        int v3 = (i0+3 < NN) ? cnt[i0+3] : 0;
        int tsum = v0+v1+v2+v3;
        int sc = tsum;
        for (int d = 1; d < 64; d <<= 1){
            int t = __shfl_up(sc, d, 64);
            if (lane >= d) sc += t;
        }
        if (lane == 63) wsums[wv] = sc;
        __syncthreads();
        int woff = 0;
        #pragma unroll
        for (int k = 0; k < 16; ++k) woff += (k < wv) ? wsums[k] : 0;
        int carry_in = carry_s;
        __syncthreads();
        if (tid == 1023) carry_s = carry_in + woff + sc;
        int excl = carry_in + woff + (sc - tsum);
        int e0 = excl, e1 = e0+v0, e2 = e1+v1, e3 = e2+v2;
        if (i0+0 < NN){ off[i0+0]=e0; cur[i0+0]=e0; }
        if (i0+1 < NN){ off[i0+1]=e1; cur[i0+1]=e1; }
        if (i0+2 < NN){ off[i0+2]=e2; cur[i0+2]=e2; }
        if (i0+3 < NN){ off[i0+3]=e3; cur[i0+3]=e3; }
        __syncthreads();
    }
}

__global__ void k_scatter(const int* __restrict__ src, const int* __restrict__ dst,
                          const float* __restrict__ ea,
                          int* cur_d, int* cur_s,
                          int* bktd, int* bkts){
    int e = blockIdx.x*blockDim.x + threadIdx.x;
    if (e >= NE) return;
    int s = src[e], d = dst[e];
    unsigned wq16 = quant_w(ea[e]) >> 3;
    int p = atomicAdd(&cur_d[d], 1);
    bktd[p] = (int)(((unsigned)s & 0xFFFFu) | (wq16 << 16));
    int q = atomicAdd(&cur_s[s], 1);
    bkts[q] = (int)(((unsigned)d & 0xFFFFu) | (wq16 << 16));
}

// ================= PNA gather + finalize + GAT1 transforms (8 lanes/node) =================
__global__ __launch_bounds__(256) void k_pna(
    const float* __restrict__ x,
    const int* __restrict__ cnt_d, const int* __restrict__ off_d,
    const int* __restrict__ adjC,
    const float* __restrict__ W_ee, const float* __restrict__ b_ee,
    const float* __restrict__ W_pre, const float* __restrict__ b_pre,
    const float* __restrict__ W_post, const float* __restrict__ b_post,
    const float* __restrict__ W_pna, const float* __restrict__ b_pna,
    const float* __restrict__ W1l, const float* __restrict__ b1l,
    const float* __restrict__ W1r, const float* __restrict__ b1r,
    float* __restrict__ xl1, float* __restrict__ xr1, float* __restrict__ ea_mean)
{
    __shared__ float sWpre[75], sWpost[520], sWpna[64], sW1l[128], sW1r[128];
    __shared__ float sbpre[5], sWee[5], sbee[5], sbpost[8], sbpna[8], sb1l[16], sb1r[16];
    for (int t=threadIdx.x; t<75;  t+=256) sWpre[t]=W_pre[t];
    for (int t=threadIdx.x; t<520; t+=256) sWpost[t]=W_post[t];
    for (int t=threadIdx.x; t<64;  t+=256) sWpna[t]=W_pna[t];
    for (int t=threadIdx.x; t<128; t+=256){ sW1l[t]=W1l[t]; sW1r[t]=W1r[t]; }
    if (threadIdx.x<5){ sbpre[threadIdx.x]=b_pre[threadIdx.x]; sWee[threadIdx.x]=W_ee[threadIdx.x]; sbee[threadIdx.x]=b_ee[threadIdx.x]; }
    if (threadIdx.x<8){ sbpost[threadIdx.x]=b_post[threadIdx.x]; sbpna[threadIdx.x]=b_pna[threadIdx.x]; }
    if (threadIdx.x<16){ sb1l[threadIdx.x]=b1l[threadIdx.x]; sb1r[threadIdx.x]=b1r[threadIdx.x]; }
    __syncthreads();
    int node = blockIdx.x*32 + (threadIdx.x>>3);
    if (node >= NN) return;
    int g = threadIdx.x & 7;
    float xd[5];
    #pragma unroll
    for (int k=0;k<5;k++) xd[k] = x[node*5+k];
    float cb[5], c1v[5];
    #pragma unroll
    for (int c=0;c<5;c++){
        float a = sbpre[c], b = 0.f;
        #pragma unroll
        for (int k=0;k<5;k++){
            a += xd[k]*sWpre[k*5+c];
            a += sbee[k]*sWpre[(10+k)*5+c];
            b += sWee[k]*sWpre[(10+k)*5+c];
        }
        cb[c]=a; c1v[c]=b;
    }
    int deg = cnt_d[node], base = off_d[node];
    float sum[5], ssq[5], mn[5], mx[5];
    #pragma unroll
    for (int c=0;c<5;c++){ sum[c]=0.f; ssq[c]=0.f; mn[c]=1e30f; mx[c]=-1e30f; }
    float wsum = 0.f;
    for (int j=g; j<deg; j+=8){
        int ent = adjC[base+j];
        int s = cent_node(ent);
        float w = cent_w(ent);
        wsum += w;
        float xs[5];
        #pragma unroll
        for (int k=0;k<5;k++) xs[k] = x[s*5+k];
        #pragma unroll
        for (int c=0;c<5;c++){
            float m = cb[c] + w*c1v[c];
            #pragma unroll
            for (int k=0;k<5;k++) m += xs[k]*sWpre[(5+k)*5+c];
            sum[c]+=m; ssq[c]+=m*m; mn[c]=fminf(mn[c],m); mx[c]=fmaxf(mx[c],m);
        }
    }
    #pragma unroll
    for (int st=1; st<8; st<<=1){
        #pragma unroll
        for (int c=0;c<5;c++){
            sum[c] += __shfl_xor(sum[c], st);
            ssq[c] += __shfl_xor(ssq[c], st);
            mn[c] = fminf(mn[c], __shfl_xor(mn[c], st));
            mx[c] = fmaxf(mx[c], __shfl_xor(mx[c], st));
        }
        wsum += __shfl_xor(wsum, st);
    }
    float c = (float)deg, cc = fmaxf(c, 1.f);
    float amp = __logf(cc+1.f) * (1.0f/AVG_DEG_LOG);
    float feat[65];
    #pragma unroll
    for (int k=0;k<5;k++) feat[k]=xd[k];
    #pragma unroll
    for (int j=0;j<5;j++){
        float mean = sum[j]/cc, msq = ssq[j]/cc;
        float sd = sqrtf(fmaxf(msq - mean*mean, 0.f) + 1e-5f);
        feat[5+j]=mean;
        feat[10+j]= (deg>0)? mn[j] : 0.f;
        feat[15+j]= (deg>0)? mx[j] : 0.f;
        feat[20+j]=sd;
    }
    #pragma unroll
    for (int j=0;j<20;j++){ feat[25+j]=feat[5+j]*amp; feat[45+j]=feat[5+j]/amp; }
    float t = sbpost[g];
    #pragma unroll
    for (int k=0;k<65;k++) t += feat[k]*sWpost[k*8+g];
    float nf = sbpna[g];
    #pragma unroll
    for (int k=0;k<8;k++) nf += __shfl(t, k, 8) * sWpna[k*8+g];
    float nfk[8];
    #pragma unroll
    for (int k=0;k<8;k++) nfk[k] = __shfl(nf, k, 8);
    #pragma unroll
    for (int u=0;u<2;u++){
        int o = 2*g+u;
        float a=sb1l[o], b2=sb1r[o];
        #pragma unroll
        for (int k=0;k<8;k++){ a += nfk[k]*sW1l[k*16+o]; b2 += nfk[k]*sW1r[k*16+o]; }
        xl1[node*16+o]=a; xr1[node*16+o]=b2;
    }
    if (g==0) ea_mean[node] = wsum/cc;
}

// ================= GAT layer 1 gather (online softmax, self-loop virtual edge) =================
__global__ __launch_bounds__(256) void k_gat1(
    const int* __restrict__ cnt_d, const int* __restrict__ off_d,
    const int* __restrict__ adjC,
    const float* __restrict__ xl1, const float* __restrict__ xr1,
    const float* __restrict__ ea_mean,
    const float* __restrict__ We1, const float* __restrict__ att1, const float* __restrict__ bias1,
    const float* __restrict__ W2l, const float* __restrict__ b2l,
    const float* __restrict__ W2r, const float* __restrict__ b2r,
    _Float16* __restrict__ xl2h, float* __restrict__ xr2)
{
    __shared__ float sWe[16], sAtt[16], sBias[16], sW2l[512], sW2r[512], sb2l[32], sb2r[32];
    for (int t=threadIdx.x; t<512; t+=256){ sW2l[t]=W2l[t]; sW2r[t]=W2r[t]; }
    if (threadIdx.x<16){ sWe[threadIdx.x]=We1[threadIdx.x]; sAtt[threadIdx.x]=att1[threadIdx.x]; sBias[threadIdx.x]=bias1[threadIdx.x]; }
    if (threadIdx.x<32){ sb2l[threadIdx.x]=b2l[threadIdx.x]; sb2r[threadIdx.x]=b2r[threadIdx.x]; }
    __syncthreads();
    int node = blockIdx.x*32 + (threadIdx.x>>3);
    if (node >= NN) return;
    int g = threadIdx.x & 7;
    float xr[16];
    #pragma unroll
    for (int k=0;k<4;k++){
        float4 v = *(const float4*)(xr1 + node*16 + k*4);
        xr[k*4]=v.x; xr[k*4+1]=v.y; xr[k*4+2]=v.z; xr[k*4+3]=v.w;
    }
    int deg = cnt_d[node], base = off_d[node];
    float eam = ea_mean[node];
    float m[4], ss[4], acc[16];
    #pragma unroll
    for (int h=0;h<4;h++){ m[h]=-1e30f; ss[h]=0.f; }
    #pragma unroll
    for (int k=0;k<16;k++) acc[k]=0.f;
    for (int j=g; j<=deg; j+=8){
        bool selfe = (j==deg);
        int s; float w;
        if (selfe){ s = node; w = eam; }
        else { int ent = adjC[base+j]; s = cent_node(ent); w = cent_w(ent); }
        float xls[16];
        #pragma unroll
        for (int k=0;k<4;k++){
            float4 v = *(const float4*)(xl1 + s*16 + k*4);
            xls[k*4]=v.x; xls[k*4+1]=v.y; xls[k*4+2]=v.z; xls[k*4+3]=v.w;
        }
        #pragma unroll
        for (int h=0;h<4;h++){
            float a = 0.f;
            #pragma unroll
            for (int ch=0;ch<4;ch++){
                int idx = h*4+ch;
                a += lrelu(xls[idx] + xr[idx] + w*sWe[idx]) * sAtt[idx];
            }
            float mn2 = fmaxf(m[h], a);
            float corr = __expf(m[h]-mn2);
            float p = __expf(a-mn2);
            ss[h] = ss[h]*corr + p;
            #pragma unroll
            for (int ch=0;ch<4;ch++){
                int idx = h*4+ch;
                acc[idx] = acc[idx]*corr + p*xls[idx];
            }
            m[h] = mn2;
        }
    }
    #pragma unroll
    for (int st=1; st<8; st<<=1){
        #pragma unroll
        for (int h=0;h<4;h++){
            float mo = __shfl_xor(m[h], st);
            float so = __shfl_xor(ss[h], st);
            float mn2 = fmaxf(m[h], mo);
            float ca = __expf(m[h]-mn2), cbb = __expf(mo-mn2);
            ss[h] = ss[h]*ca + so*cbb;
            #pragma unroll
            for (int ch=0;ch<4;ch++){
                int idx=h*4+ch;
                float ao = __shfl_xor(acc[idx], st);
                acc[idx] = acc[idx]*ca + ao*cbb;
            }
            m[h]=mn2;
        }
    }
    float nf1[16];
    #pragma unroll
    for (int h=0;h<4;h++){
        float den = ss[h] + 1e-16f;
        #pragma unroll
        for (int ch=0;ch<4;ch++){
            int idx=h*4+ch;
            nf1[idx] = relu(acc[idx]/den + sBias[idx]);
        }
    }
    #pragma unroll
    for (int u=0;u<4;u++){
        int o = g + 8*u;
        float a=sb2l[o], b=sb2r[o];
        #pragma unroll
        for (int k=0;k<16;k++){ a += nf1[k]*sW2l[k*32+o]; b += nf1[k]*sW2r[k*32+o]; }
        xl2h[(size_t)node*32+o] = (_Float16)a;
        xr2[node*32+o]=b;
    }
}

// ================= GAT layer 2 gather + Wn MLP + We_fc projections =================
__global__ __launch_bounds__(256) void k_gat2(
    const int* __restrict__ cnt_d, const int* __restrict__ off_d,
    const int* __restrict__ adjC,
    const _Float16* __restrict__ xl2h, const float* __restrict__ xr2,
    const float* __restrict__ ea_mean,
    const float* __restrict__ We2, const float* __restrict__ att2, const float* __restrict__ bias2,
    const float* __restrict__ Wn, const float* __restrict__ bn,
    const float* __restrict__ We_fc,
    _Float16* __restrict__ Ps16, _Float16* __restrict__ Pd16,
    float* __restrict__ Ps01, float* __restrict__ Pd01)
{
    __shared__ float sWe[32], sAtt[32], sBias[32], sWn[1024], sbn[32];
    __shared__ float sWsrc[1024], sWdst[1024];
    for (int t=threadIdx.x; t<1024; t+=256){
        sWn[t]=Wn[t];
        sWsrc[t]=We_fc[32 + t];
        sWdst[t]=We_fc[33*32 + t];
    }
    if (threadIdx.x<32){ sWe[threadIdx.x]=We2[threadIdx.x]; sAtt[threadIdx.x]=att2[threadIdx.x];
                         sBias[threadIdx.x]=bias2[threadIdx.x]; sbn[threadIdx.x]=bn[threadIdx.x]; }
    __syncthreads();
    int node = blockIdx.x*32 + (threadIdx.x>>3);
    if (node >= NN) return;
    int g = threadIdx.x & 7;
    float xr[32];
    #pragma unroll
    for (int k=0;k<8;k++){
        float4 v = *(const float4*)(xr2 + node*32 + k*4);
        xr[k*4]=v.x; xr[k*4+1]=v.y; xr[k*4+2]=v.z; xr[k*4+3]=v.w;
    }
    int deg = cnt_d[node], base = off_d[node];
    float eam = ea_mean[node];
    float m[4], ss[4], acc[32];
    #pragma unroll
    for (int h=0;h<4;h++){ m[h]=-1e30f; ss[h]=0.f; }
    #pragma unroll
    for (int k=0;k<32;k++) acc[k]=0.f;
    for (int j=g; j<=deg; j+=8){
        bool selfe = (j==deg);
        int s; float w;
        if (selfe){ s = node; w = eam; }
        else { int ent = adjC[base+j]; s = cent_node(ent); w = cent_w(ent); }
        float xls[32];
        const h8v* xp = (const h8v*)(xl2h + (size_t)s*32);
        #pragma unroll
        for (int k=0;k<4;k++){
            h8v hv = xp[k];
            #pragma unroll
            for (int u=0;u<8;u++) xls[k*8+u] = (float)hv[u];
        }
        #pragma unroll
        for (int h=0;h<4;h++){
            float a = 0.f;
            #pragma unroll
            for (int ch=0;ch<8;ch++){
                int idx = h*8+ch;
                a += lrelu(xls[idx] + xr[idx] + w*sWe[idx]) * sAtt[idx];
            }
            float mn2 = fmaxf(m[h], a);
            float corr = __expf(m[h]-mn2);
            float p = __expf(a-mn2);
            ss[h] = ss[h]*corr + p;
            #pragma unroll
            for (int ch=0;ch<8;ch++){
                int idx = h*8+ch;
                acc[idx] = acc[idx]*corr + p*xls[idx];
            }
            m[h] = mn2;
        }
    }
    #pragma unroll
    for (int st=1; st<8; st<<=1){
        #pragma unroll
        for (int h=0;h<4;h++){
            float mo = __shfl_xor(m[h], st);
            float so = __shfl_xor(ss[h], st);
            float mn2 = fmaxf(m[h], mo);
            float ca = __expf(m[h]-mn2), cbb = __expf(mo-mn2);
            ss[h] = ss[h]*ca + so*cbb;
            #pragma unroll
            for (int ch=0;ch<8;ch++){
                int idx=h*8+ch;
                float ao = __shfl_xor(acc[idx], st);
                acc[idx] = acc[idx]*ca + ao*cbb;
            }
            m[h]=mn2;
        }
    }
    float nf2[32];
    #pragma unroll
    for (int h=0;h<4;h++){
        float den = ss[h] + 1e-16f;
        #pragma unroll
        for (int ch=0;ch<8;ch++){
            int idx=h*8+ch;
            nf2[idx] = relu(acc[idx]/den + sBias[idx]);
        }
    }
    float mine[4];
    #pragma unroll
    for (int u=0;u<4;u++){
        int oo = g + 8*u;
        float a = sbn[oo];
        #pragma unroll
        for (int k=0;k<32;k++) a += nf2[k]*sWn[k*32+oo];
        mine[u] = relu(a);
    }
    float nfn[32];
    #pragma unroll
    for (int k=0;k<32;k++) nfn[k] = __shfl(mine[k>>3], k&7, 8);
    float pa[4], pb[4];
    #pragma unroll
    for (int u=0;u<4;u++){
        int oo = g + 8*u;
        float a=0.f, b=0.f;
        #pragma unroll
        for (int k=0;k<32;k++){ a += nfn[k]*sWsrc[k*32+oo]; b += nfn[k]*sWdst[k*32+oo]; }
        pa[u]=a; pb[u]=b;
        Ps16[(size_t)node*32+oo] = (_Float16)a;
        Pd16[(size_t)node*32+oo] = (_Float16)b;
    }
    float ps0=__shfl(pa[0],0,8), ps1=__shfl(pa[0],1,8);
    float pd0=__shfl(pb[0],0,8), pd1=__shfl(pb[0],1,8);
    if (g==0){
        *(float2*)(Ps01 + node*2) = make_float2(ps0, ps1);
        *(float2*)(Pd01 + node*2) = make_float2(pd0, pd1);
    }
}

// ================= per-src softmax stats from COARSE src buffer (single read) =================
__global__ __launch_bounds__(1024) void k_src_bins(
    const int2* __restrict__ cS, const int* __restrict__ binStartS,
    const float* __restrict__ Ps01, const float* __restrict__ Pd01,
    const float* __restrict__ We_fc, const float* __restrict__ be_fc,
    float4* __restrict__ ssd)
{
    __shared__ float sPs0[256], sPs1[256];
    __shared__ unsigned sM0[256], sM1[256];
    __shared__ float sS0[256], sS1[256];
    __shared__ float cW00, cW01, cbe0, cbe1;
    int bin = blockIdx.x, tid = threadIdx.x;
    if (tid == 0){ cW00=We_fc[0]; cW01=We_fc[1]; cbe0=be_fc[0]; cbe1=be_fc[1]; }
    if (tid < 256){
        int node = (bin<<8) + tid;
        float2 p = (node < NN) ? *(const float2*)(Ps01 + node*2) : make_float2(0.f,0.f);
        sPs0[tid]=p.x; sPs1[tid]=p.y;
        sM0[tid]=fenc(-1e30f); sM1[tid]=fenc(-1e30f);
        sS0[tid]=0.f; sS1[tid]=0.f;
    }
    __syncthreads();
    int S = binStartS[bin], E = binStartS[bin+1];
    const int REG = 9;
    float ra0[REG], ra1[REG]; int rl[REG];
    int n = 0;
    // pass 1: per-node max, caching scores in registers (compile-time indices)
    {
        int idx = S + tid;
        #pragma unroll
        for (int it = 0; it < REG; ++it){
            if (idx < E){
                int2 ent = cS[idx];
                unsigned y = (unsigned)ent.y;
                int local = y >> 24;
                int d = ent.x;
                float w = ((float)(y & 0x7FFFFu) + 0.5f) * (1.0f/524288.0f);
                float2 q = *(const float2*)(Pd01 + d*2);
                float a0 = cbe0 + sPs0[local] + w*cW00 + q.x;
                float a1 = cbe1 + sPs1[local] + w*cW01 + q.y;
                ra0[it]=a0; ra1[it]=a1; rl[it]=local; n = it+1;
                atomicMax(&sM0[local], fenc(a0));
                atomicMax(&sM1[local], fenc(a1));
            }
            idx += 1024;
        }
        // overflow tail (rare)
        for (int i = S + tid + REG*1024; i < E; i += 1024){
            int2 ent = cS[i];
            unsigned y = (unsigned)ent.y;
            int local = y >> 24;
            int d = ent.x;
            float w = ((float)(y & 0x7FFFFu) + 0.5f) * (1.0f/524288.0f);
            float2 q = *(const float2*)(Pd01 + d*2);
            atomicMax(&sM0[local], fenc(cbe0 + sPs0[local] + w*cW00 + q.x));
            atomicMax(&sM1[local], fenc(cbe1 + sPs1[local] + w*cW01 + q.y));
        }
    }
    __syncthreads();
    // pass 2: exp-sum from registers
    #pragma unroll
    for (int it = 0; it < REG; ++it){
        if (it < n){
            atomicAdd(&sS0[rl[it]], __expf(ra0[it] - fdec(sM0[rl[it]])));
            atomicAdd(&sS1[rl[it]], __expf(ra1[it] - fdec(sM1[rl[it]])));
        }
    }
    for (int i = S + tid + REG*1024; i < E; i += 1024){
        int2 ent = cS[i];
        unsigned y = (unsigned)ent.y;
        int local = y >> 24;
        int d = ent.x;
        float w = ((float)(y & 0x7FFFFu) + 0.5f) * (1.0f/524288.0f);
        float2 q = *(const float2*)(Pd01 + d*2);
        atomicAdd(&sS0[local], __expf(cbe0 + sPs0[local] + w*cW00 + q.x - fdec(sM0[local])));
        atomicAdd(&sS1[local], __expf(cbe1 + sPs1[local] + w*cW01 + q.y - fdec(sM1[local])));
    }
    __syncthreads();
    if (tid < 256){
        int node = (bin<<8) + tid;
        if (node < NN) ssd[node] = make_float4(fdec(sM0[tid]), fdec(sM1[tid]), sS0[tid], sS1[tid]);
    }
}

// ================= per-src softmax stats (fallback: compact 4B entries) =================
__global__ __launch_bounds__(256) void k_src(
    const int* __restrict__ cnt_s, const int* __restrict__ off_s,
    const int* __restrict__ bkts,
    const float* __restrict__ Ps01, const float* __restrict__ Pd01,
    const float* __restrict__ We_fc, const float* __restrict__ be_fc,
    float4* __restrict__ ssd)
{
    __shared__ float sW00, sW01, sbe0, sbe1;
    if (threadIdx.x == 0){ sW00=We_fc[0]; sW01=We_fc[1]; sbe0=be_fc[0]; sbe1=be_fc[1]; }
    __syncthreads();
    int node = blockIdx.x*32 + (threadIdx.x>>3);
    if (node >= NN) return;
    int g = threadIdx.x & 7;
    float2 p = *(const float2*)(Ps01 + node*2);
    float base0 = sbe0 + p.x, base1 = sbe1 + p.y;
    int deg = cnt_s[node], base = off_s[node];
    float m0=-1e30f, m1=-1e30f, s0=0.f, s1=0.f;
    for (int j=g; j<deg; j+=8){
        int ent = bkts[base+j];
        int d = cent_node(ent);
        float w = cent_w(ent);
        float2 q = *(const float2*)(Pd01 + d*2);
        float a0 = base0 + w*sW00 + q.x;
        float a1 = base1 + w*sW01 + q.y;
        float mn0 = fmaxf(m0, a0);
        s0 = s0*__expf(m0-mn0) + __expf(a0-mn0); m0 = mn0;
        float mn1 = fmaxf(m1, a1);
        s1 = s1*__expf(m1-mn1) + __expf(a1-mn1); m1 = mn1;
    }
    #pragma unroll
    for (int st=1; st<8; st<<=1){
        float mo = __shfl_xor(m0, st), so = __shfl_xor(s0, st);
        float mn = fmaxf(m0, mo);
        s0 = s0*__expf(m0-mn) + so*__expf(mo-mn); m0 = mn;
        mo = __shfl_xor(m1, st); so = __shfl_xor(s1, st);
        mn = fmaxf(m1, mo);
        s1 = s1*__expf(m1-mn) + so*__expf(mo-mn); m1 = mn;
    }
    if (g==0) ssd[node] = make_float4(m0, m1, s0, s1);
}

// ================= final edge scores (eid-ordered: streaming writes) =================
__global__ __launch_bounds__(256) void k_scF(
    const int* __restrict__ src, const int* __restrict__ dst, const float* __restrict__ ea,
    const _Float16* __restrict__ Ps16, const _Float16* __restrict__ Pd16,
    const float* __restrict__ We_fc, const float* __restrict__ be_fc,
    const float4* __restrict__ ssd,
    float* __restrict__ out)
{
    __shared__ float sW0[32], sB[32];
    if (threadIdx.x < 32){ sW0[threadIdx.x]=We_fc[threadIdx.x]; sB[threadIdx.x]=be_fc[threadIdx.x]; }
    __syncthreads();
    int e = blockIdx.x*blockDim.x + threadIdx.x;
    if (e >= NE) return;
    int s = src[e], d = dst[e];
    float w = ea[e];
    const h8v* ps = (const h8v*)(Ps16 + (size_t)s*32);
    const h8v* pd = (const h8v*)(Pd16 + (size_t)d*32);
    float o[32];
    #pragma unroll
    for (int k=0;k<4;k++){
        h8v a = ps[k], b = pd[k];
        #pragma unroll
        for (int u=0;u<8;u++){
            int j = k*8+u;
            o[j] = sB[j] + w*sW0[j] + (float)a[u] + (float)b[u];
        }
    }
    float4 v = ssd[s];
    o[0] = __expf(o[0] - v.x) / (v.z + 1e-16f);
    o[1] = __expf(o[1] - v.y) / (v.w + 1e-16f);
    float* op = out + (size_t)e*32;
    #pragma unroll
    for (int j=0;j<8;j++){
        f4v ov; ov.x=o[j*4]; ov.y=o[j*4+1]; ov.z=o[j*4+2]; ov.w=o[j*4+3];
        __builtin_nontemporal_store(ov, (f4v*)(op + j*4));
    }
}

extern "C" void kernel_launch(void* const* d_in, const int* in_sizes, int n_in,
                              void* d_out, int out_size, void* d_ws, size_t ws_size,
                              hipStream_t stream) {
    const float* x     = (const float*)d_in[0];
    const int*   ei    = (const int*)  d_in[1];
    const float* ea    = (const float*)d_in[2];
    const float* W_ee  = (const float*)d_in[3];  const float* b_ee  = (const float*)d_in[4];
    const float* W_pre = (const float*)d_in[5];  const float* b_pre = (const float*)d_in[6];
    const float* W_post= (const float*)d_in[7];  const float* b_post= (const float*)d_in[8];
    const float* W_pna = (const float*)d_in[9];  const float* b_pna = (const float*)d_in[10];
    const float* W1l   = (const float*)d_in[11]; const float* b1l   = (const float*)d_in[12];
    const float* W1r   = (const float*)d_in[13]; const float* b1r   = (const float*)d_in[14];
    const float* W1e   = (const float*)d_in[15]; const float* att1  = (const float*)d_in[16];
    const float* bias1 = (const float*)d_in[17];
    const float* W2l   = (const float*)d_in[18]; const float* b2l   = (const float*)d_in[19];
    const float* W2r   = (const float*)d_in[20]; const float* b2r   = (const float*)d_in[21];
    const float* W2e   = (const float*)d_in[22]; const float* att2  = (const float*)d_in[23];
    const float* bias2 = (const float*)d_in[24];
    const float* Wn    = (const float*)d_in[25]; const float* bn    = (const float*)d_in[26];
    const float* We_fc = (const float*)d_in[27]; const float* be_fc = (const float*)d_in[28];
    const int* src = ei;
    const int* dst = ei + NE;
    float* out = (float*)d_out;

    float* ws = (float*)d_ws;
    size_t o = 0;
    auto A = [&](size_t n){ size_t r = o; o = (o + n + 63) & ~(size_t)63; return r; };
    int*   cnt_d  = (int*)(ws + A(NN));
    int*   off_d  = (int*)(ws + A(NN));
    int*   cnt_s  = (int*)(ws + A(NN));
    int*   off_s  = (int*)(ws + A(NN));
    int*   cur_d  = (int*)(ws + A(NN));
    int*   cur_s  = (int*)(ws + A(NN));
    float* xl1    =        ws + A((size_t)NN*16);
    float* xr1    =        ws + A((size_t)NN*16);
    _Float16* xl2h = (_Float16*)(ws + A((size_t)NN*16));   // NN*32 halfs
    float* xr2    =        ws + A((size_t)NN*32);
    _Float16* Ps16 = (_Float16*)(ws + A((size_t)NN*16));   // NN*32 halfs
    _Float16* Pd16 = (_Float16*)(ws + A((size_t)NN*16));   // NN*32 halfs
    float* ea_mean=        ws + A(NN);
    float* Ps01   =        ws + A((size_t)NN*2);
    float* Pd01   =        ws + A((size_t)NN*2);
    float4* ssd   = (float4*)(ws + A((size_t)NN*4));
    int*   histD  = (int*)(ws + A((size_t)NBIN*NCHUNK));
    int*   histS  = (int*)(ws + A((size_t)NBIN*NCHUNK));
    int*   baseD  = (int*)(ws + A((size_t)NBIN*NCHUNK));
    int*   baseS  = (int*)(ws + A((size_t)NBIN*NCHUNK));
    int*   binTotal  = (int*)(ws + A(2*NBIN));
    int*   binStartD = (int*)(ws + A(NBIN+1));
    int*   binStartS = (int*)(ws + A(NBIN+1));
    int*   adjC  = (int*)(ws + A((size_t)NE));     // dst adjacency (4B compact)
    int*   bktsC = (int*)(ws + A((size_t)NE));     // fallback src adjacency (4B)
    size_t o_fallback = o;
    int2*  bufY = (int2*)(ws + A(2*(size_t)NE));   // coarse dst
    int2*  bufZ = (int2*)(ws + A(2*(size_t)NE));   // coarse src (persists to k_src_bins)
    size_t o_sort = o;
    bool sortmode = (ws_size >= o_sort * sizeof(float));
    if (!sortmode && ws_size < o_fallback * sizeof(float)) return;  // fail loudly

    const int BS = 256;
    const int gridE = (NE + BS - 1)/BS;
    const int gridN = (NN + BS - 1)/BS;
    const int gridO = (NN + 31)/32;

    if (sortmode){
        k_hist<<<NCHUNK, BS, 0, stream>>>(src, dst, histD, histS);
        k_binsum<<<2*NBIN, BS, 0, stream>>>(histD, histS, binTotal);
        k_chunkpfx<<<2*NBIN, BS, 0, stream>>>(histD, histS, binTotal, binStartD, binStartS, baseD, baseS);
        k_coarse<<<NCHUNK, BS, 0, stream>>>(src, dst, ea, baseD, baseS, bufY, bufZ);
        k_fine<<<NBIN, BS, 0, stream>>>(bufY, binStartD, adjC, cnt_d, off_d);
    } else {
        k_zero<<<gridN, BS, 0, stream>>>(cnt_d, cnt_s);
        k_count<<<gridE, BS, 0, stream>>>(src, dst, cnt_d, cnt_s);
        k_scanCSR<<<2, 1024, 0, stream>>>(cnt_d, cnt_s, off_d, cur_d, off_s, cur_s);
        k_scatter<<<gridE, BS, 0, stream>>>(src, dst, ea, cur_d, cur_s, adjC, bktsC);
    }
    k_pna<<<gridO, BS, 0, stream>>>(x, cnt_d, off_d, adjC,
                                    W_ee, b_ee, W_pre, b_pre, W_post, b_post, W_pna, b_pna,
                                    W1l, b1l, W1r, b1r, xl1, xr1, ea_mean);
    k_gat1<<<gridO, BS, 0, stream>>>(cnt_d, off_d, adjC, xl1, xr1, ea_mean,
                                     W1e, att1, bias1, W2l, b2l, W2r, b2r, xl2h, xr2);
    k_gat2<<<gridO, BS, 0, stream>>>(cnt_d, off_d, adjC, xl2h, xr2, ea_mean,
                                     W2e, att2, bias2, Wn, bn, We_fc,
                                     Ps16, Pd16, Ps01, Pd01);
    if (sortmode){
        k_src_bins<<<NBIN, 1024, 0, stream>>>(bufZ, binStartS, Ps01, Pd01, We_fc, be_fc, ssd);
    } else {
        k_src<<<gridO, BS, 0, stream>>>(cnt_s, off_s, bktsC, Ps01, Pd01, We_fc, be_fc, ssd);
    }
    k_scF<<<gridE, BS, 0, stream>>>(src, dst, ea, Ps16, Pd16, We_fc, be_fc, ssd, out);
}

// Round 10
// 290.325 us; speedup vs baseline: 2.2610x; 2.2610x over previous
//
#include <hip/hip_runtime.h>
#include <math.h>

#define NN 50000
#define NE 1600000
#define AVG_DEG_LOG 3.4965075614664802f
#define NBIN 196            // (NN+255)/256
#define CHUNK 4096
#define NCHUNK 391          // (NE+CHUNK-1)/CHUNK

typedef float f4v __attribute__((ext_vector_type(4)));
typedef _Float16 h4v __attribute__((ext_vector_type(4)));
typedef _Float16 h8v __attribute__((ext_vector_type(8)));

__device__ __forceinline__ float lrelu(float x){ return x > 0.f ? x : 0.2f*x; }
__device__ __forceinline__ float relu(float x){ return x > 0.f ? x : 0.f; }

// coarse entry (int2): x = other_node, y = local8<<24 | w_q19
__device__ __forceinline__ unsigned quant_w(float w){
    unsigned wq = (unsigned)(w * 524288.f);
    return wq > 524287u ? 524287u : wq;
}
// compact 4-byte adjacency entry: node16 | wq16<<16
__device__ __forceinline__ int cent_node(int e){ return e & 0xFFFF; }
__device__ __forceinline__ float cent_w(int e){
    return ((float)(((unsigned)e >> 16) & 0xFFFFu) + 0.5f) * (1.0f/65536.0f);
}
// order-preserving float<->uint encoding (for LDS atomicMax on floats)
__device__ __forceinline__ unsigned fenc(float f){
    unsigned b = __float_as_uint(f);
    return (b & 0x80000000u) ? ~b : (b | 0x80000000u);
}
__device__ __forceinline__ float fdec(unsigned u){
    unsigned b = (u & 0x80000000u) ? (u & 0x7FFFFFFFu) : ~u;
    return __uint_as_float(b);
}

// ================= two-level counting sort (no global atomics) =================

__global__ __launch_bounds__(256) void k_hist(const int* __restrict__ src, const int* __restrict__ dst,
                                              int* __restrict__ histD, int* __restrict__ histS){
    __shared__ int hd[NBIN], hs[NBIN];
    for (int t=threadIdx.x; t<NBIN; t+=256){ hd[t]=0; hs[t]=0; }
    __syncthreads();
    int chunk = blockIdx.x;
    int e0 = chunk*CHUNK, e1 = min(e0+CHUNK, NE);
    for (int e=e0+threadIdx.x; e<e1; e+=256){
        atomicAdd(&hd[dst[e]>>8], 1);
        atomicAdd(&hs[src[e]>>8], 1);
    }
    __syncthreads();
    for (int t=threadIdx.x; t<NBIN; t+=256){
        histD[t*NCHUNK+chunk] = hd[t];
        histS[t*NCHUNK+chunk] = hs[t];
    }
}

// stage 1: per-bin totals (grid = 2*NBIN)
__global__ __launch_bounds__(256) void k_binsum(const int* __restrict__ histD, const int* __restrict__ histS,
                                                int* __restrict__ binTotal){
    __shared__ int wsum[4];
    int dir = blockIdx.x / NBIN, bin = blockIdx.x % NBIN;
    const int* hist = dir ? histS : histD;
    int s = 0;
    for (int t=threadIdx.x; t<NCHUNK; t+=256) s += hist[bin*NCHUNK + t];
    #pragma unroll
    for (int st=32; st>=1; st>>=1) s += __shfl_xor(s, st);
    if ((threadIdx.x & 63) == 0) wsum[threadIdx.x>>6] = s;
    __syncthreads();
    if (threadIdx.x == 0) binTotal[dir*NBIN + bin] = wsum[0]+wsum[1]+wsum[2]+wsum[3];
}

// stage 2 (fused): binStart from binTotal prefix + per-bin chunk prefix (grid = 2*NBIN)
__global__ __launch_bounds__(256) void k_chunkpfx(const int* __restrict__ histD, const int* __restrict__ histS,
                                                  const int* __restrict__ binTotal,
                                                  int* __restrict__ binStartD, int* __restrict__ binStartS,
                                                  int* __restrict__ baseD, int* __restrict__ baseS){
    __shared__ int wsums[4];
    __shared__ int sbase;
    int dir = blockIdx.x / NBIN, bin = blockIdx.x % NBIN;
    const int* hist = dir ? histS : histD;
    int* binStart = dir ? binStartS : binStartD;
    int* base = dir ? baseS : baseD;
    int tid = threadIdx.x, lane = tid & 63, wv = tid >> 6;
    {
        int s = 0;
        for (int k = tid; k < bin; k += 256) s += binTotal[dir*NBIN + k];
        #pragma unroll
        for (int st=32; st>=1; st>>=1) s += __shfl_xor(s, st);
        if (lane == 0) wsums[wv] = s;
        __syncthreads();
        if (tid == 0){
            sbase = wsums[0]+wsums[1]+wsums[2]+wsums[3];
            binStart[bin] = sbase;
            if (bin == 0) binStart[NBIN] = NE;
        }
        __syncthreads();
    }
    int bS = sbase;
    __syncthreads();
    int i0 = tid*2, i1 = tid*2+1;
    int a = (i0 < NCHUNK) ? hist[bin*NCHUNK + i0] : 0;
    int b = (i1 < NCHUNK) ? hist[bin*NCHUNK + i1] : 0;
    int v = a + b;
    int sc = v;
    for (int d = 1; d < 64; d <<= 1){
        int t = __shfl_up(sc, d, 64);
        if (lane >= d) sc += t;
    }
    if (lane == 63) wsums[wv] = sc;
    __syncthreads();
    int woff = 0;
    #pragma unroll
    for (int k = 0; k < 4; ++k) woff += (k < wv) ? wsums[k] : 0;
    int excl = bS + woff + sc - v;
    if (i0 < NCHUNK) base[bin*NCHUNK + i0] = excl;
    if (i1 < NCHUNK) base[bin*NCHUNK + i1] = excl + a;
}

__global__ __launch_bounds__(256) void k_coarse(const int* __restrict__ src, const int* __restrict__ dst,
                                                const float* __restrict__ ea,
                                                const int* __restrict__ baseD, const int* __restrict__ baseS,
                                                int2* __restrict__ cD, int2* __restrict__ cS){
    __shared__ int curd[NBIN], curs[NBIN];
    int chunk = blockIdx.x;
    for (int t=threadIdx.x; t<NBIN; t+=256){
        curd[t] = baseD[t*NCHUNK+chunk];
        curs[t] = baseS[t*NCHUNK+chunk];
    }
    __syncthreads();
    int e0 = chunk*CHUNK, e1 = min(e0+CHUNK, NE);
    for (int e=e0+threadIdx.x; e<e1; e+=256){
        int s = src[e], d = dst[e];
        unsigned wq = quant_w(ea[e]);
        int pd = atomicAdd(&curd[d>>8], 1);
        cD[pd] = make_int2(s, (int)(((unsigned)(d & 255) << 24) | wq));
        int ps = atomicAdd(&curs[s>>8], 1);
        cS[ps] = make_int2(d, (int)(((unsigned)(s & 255) << 24) | wq));
    }
}

// fine sort, dst direction: compact 4B entries out
__global__ __launch_bounds__(256) void k_fine(const int2* __restrict__ cin,
                                              const int* __restrict__ binStart,
                                              int* __restrict__ bout,
                                              int* __restrict__ cnt, int* __restrict__ off){
    __shared__ int h[256], cur[256];
    __shared__ int ws4[4];
    int bin = blockIdx.x;
    int S = binStart[bin], E = binStart[bin+1];
    h[threadIdx.x] = 0;
    __syncthreads();
    for (int i = S + threadIdx.x; i < E; i += 256){
        unsigned y = (unsigned)cin[i].y;
        atomicAdd(&h[y >> 24], 1);
    }
    __syncthreads();
    int v = h[threadIdx.x];
    int lane = threadIdx.x & 63, wv = threadIdx.x >> 6;
    int sc = v;
    for (int d = 1; d < 64; d <<= 1){
        int t = __shfl_up(sc, d, 64);
        if (lane >= d) sc += t;
    }
    if (lane == 63) ws4[wv] = sc;
    __syncthreads();
    int woff = 0;
    #pragma unroll
    for (int k = 0; k < 4; ++k) woff += (k < wv) ? ws4[k] : 0;
    int excl = woff + sc - v;
    cur[threadIdx.x] = S + excl;
    int node = (bin << 8) + threadIdx.x;
    if (node < NN){ cnt[node] = v; off[node] = S + excl; }
    __syncthreads();
    for (int i = S + threadIdx.x; i < E; i += 256){
        int2 ent = cin[i];
        unsigned y = (unsigned)ent.y;
        int local = y >> 24;
        int pos = atomicAdd(&cur[local], 1);
        unsigned wq16 = (y & 0x7FFFFu) >> 3;
        bout[pos] = (int)(((unsigned)ent.x & 0xFFFFu) | (wq16 << 16));
    }
}

// ================= fallback CSR path (atomic scatter) =================

__global__ void k_zero(int* cnt_d, int* cnt_s){
    int i = blockIdx.x*blockDim.x + threadIdx.x;
    if (i < NN){ cnt_d[i]=0; cnt_s[i]=0; }
}

__global__ void k_count(const int* __restrict__ src, const int* __restrict__ dst,
                        int* cnt_d, int* cnt_s){
    int e = blockIdx.x*blockDim.x + threadIdx.x;
    if (e >= NE) return;
    atomicAdd(&cnt_d[dst[e]], 1);
    atomicAdd(&cnt_s[src[e]], 1);
}

__global__ __launch_bounds__(1024) void k_scanCSR(const int* __restrict__ cnt_d, const int* __restrict__ cnt_s,
                                                  int* off_d, int* cur_d, int* off_s, int* cur_s){
    __shared__ int wsums[16];
    __shared__ int carry_s;
    const int tid = threadIdx.x, lane = tid & 63, wv = tid >> 6;
    const int pass = blockIdx.x;
    const int* cnt = pass ? cnt_s : cnt_d;
    int* off = pass ? off_s : off_d;
    int* cur = pass ? cur_s : cur_d;
    if (tid == 0) carry_s = 0;
    __syncthreads();
    for (int base = 0; base < NN; base += 4096){
        int i0 = base + tid*4;
        int v0 = (i0+0 < NN) ? cnt[i0+0] : 0;
        int v1 = (i0+1 < NN) ? cnt[i0+1] : 0;
        int v2 = (i0+2 < NN) ? cnt[i0+2] : 0;
        int v3 = (i0+3 < NN) ? cnt[i0+3] : 0;
        int tsum = v0+v1+v2+v3;
        int sc = tsum;
        for (int d = 1; d < 64; d <<= 1){
            int t = __shfl_up(sc, d, 64);
            if (lane >= d) sc += t;
        }
        if (lane == 63) wsums[wv] = sc;
        __syncthreads();
        int woff = 0;
        #pragma unroll
        for (int k = 0; k < 16; ++k) woff += (k < wv) ? wsums[k] : 0;
        int carry_in = carry_s;
        __syncthreads();
        if (tid == 1023) carry_s = carry_in + woff + sc;
        int excl = carry_in + woff + (sc - tsum);
        int e0 = excl, e1 = e0+v0, e2 = e1+v1, e3 = e2+v2;
        if (i0+0 < NN){ off[i0+0]=e0; cur[i0+0]=e0; }
        if (i0+1 < NN){ off[i0+1]=e1; cur[i0+1]=e1; }
        if (i0+2 < NN){ off[i0+2]=e2; cur[i0+2]=e2; }
        if (i0+3 < NN){ off[i0+3]=e3; cur[i0+3]=e3; }
        __syncthreads();
    }
}

__global__ void k_scatter(const int* __restrict__ src, const int* __restrict__ dst,
                          const float* __restrict__ ea,
                          int* cur_d, int* cur_s,
                          int* bktd, int* bkts){
    int e = blockIdx.x*blockDim.x + threadIdx.x;
    if (e >= NE) return;
    int s = src[e], d = dst[e];
    unsigned wq16 = quant_w(ea[e]) >> 3;
    int p = atomicAdd(&cur_d[d], 1);
    bktd[p] = (int)(((unsigned)s & 0xFFFFu) | (wq16 << 16));
    int q = atomicAdd(&cur_s[s], 1);
    bkts[q] = (int)(((unsigned)d & 0xFFFFu) | (wq16 << 16));
}

// ================= PNA gather + finalize + GAT1 transforms (8 lanes/node) =================
__global__ __launch_bounds__(256) void k_pna(
    const float* __restrict__ x,
    const int* __restrict__ cnt_d, const int* __restrict__ off_d,
    const int* __restrict__ adjC,
    const float* __restrict__ W_ee, const float* __restrict__ b_ee,
    const float* __restrict__ W_pre, const float* __restrict__ b_pre,
    const float* __restrict__ W_post, const float* __restrict__ b_post,
    const float* __restrict__ W_pna, const float* __restrict__ b_pna,
    const float* __restrict__ W1l, const float* __restrict__ b1l,
    const float* __restrict__ W1r, const float* __restrict__ b1r,
    float* __restrict__ xl1, float* __restrict__ xr1, float* __restrict__ ea_mean)
{
    __shared__ float sWpre[75], sWpost[520], sWpna[64], sW1l[128], sW1r[128];
    __shared__ float sbpre[5], sWee[5], sbee[5], sbpost[8], sbpna[8], sb1l[16], sb1r[16];
    for (int t=threadIdx.x; t<75;  t+=256) sWpre[t]=W_pre[t];
    for (int t=threadIdx.x; t<520; t+=256) sWpost[t]=W_post[t];
    for (int t=threadIdx.x; t<64;  t+=256) sWpna[t]=W_pna[t];
    for (int t=threadIdx.x; t<128; t+=256){ sW1l[t]=W1l[t]; sW1r[t]=W1r[t]; }
    if (threadIdx.x<5){ sbpre[threadIdx.x]=b_pre[threadIdx.x]; sWee[threadIdx.x]=W_ee[threadIdx.x]; sbee[threadIdx.x]=b_ee[threadIdx.x]; }
    if (threadIdx.x<8){ sbpost[threadIdx.x]=b_post[threadIdx.x]; sbpna[threadIdx.x]=b_pna[threadIdx.x]; }
    if (threadIdx.x<16){ sb1l[threadIdx.x]=b1l[threadIdx.x]; sb1r[threadIdx.x]=b1r[threadIdx.x]; }
    __syncthreads();
    int node = blockIdx.x*32 + (threadIdx.x>>3);
    if (node >= NN) return;
    int g = threadIdx.x & 7;
    float xd[5];
    #pragma unroll
    for (int k=0;k<5;k++) xd[k] = x[node*5+k];
    float cb[5], c1v[5];
    #pragma unroll
    for (int c=0;c<5;c++){
        float a = sbpre[c], b = 0.f;
        #pragma unroll
        for (int k=0;k<5;k++){
            a += xd[k]*sWpre[k*5+c];
            a += sbee[k]*sWpre[(10+k)*5+c];
            b += sWee[k]*sWpre[(10+k)*5+c];
        }
        cb[c]=a; c1v[c]=b;
    }
    int deg = cnt_d[node], base = off_d[node];
    float sum[5], ssq[5], mn[5], mx[5];
    #pragma unroll
    for (int c=0;c<5;c++){ sum[c]=0.f; ssq[c]=0.f; mn[c]=1e30f; mx[c]=-1e30f; }
    float wsum = 0.f;
    for (int j=g; j<deg; j+=8){
        int ent = adjC[base+j];
        int s = cent_node(ent);
        float w = cent_w(ent);
        wsum += w;
        float xs[5];
        #pragma unroll
        for (int k=0;k<5;k++) xs[k] = x[s*5+k];
        #pragma unroll
        for (int c=0;c<5;c++){
            float m = cb[c] + w*c1v[c];
            #pragma unroll
            for (int k=0;k<5;k++) m += xs[k]*sWpre[(5+k)*5+c];
            sum[c]+=m; ssq[c]+=m*m; mn[c]=fminf(mn[c],m); mx[c]=fmaxf(mx[c],m);
        }
    }
    #pragma unroll
    for (int st=1; st<8; st<<=1){
        #pragma unroll
        for (int c=0;c<5;c++){
            sum[c] += __shfl_xor(sum[c], st);
            ssq[c] += __shfl_xor(ssq[c], st);
            mn[c] = fminf(mn[c], __shfl_xor(mn[c], st));
            mx[c] = fmaxf(mx[c], __shfl_xor(mx[c], st));
        }
        wsum += __shfl_xor(wsum, st);
    }
    float c = (float)deg, cc = fmaxf(c, 1.f);
    float amp = __logf(cc+1.f) * (1.0f/AVG_DEG_LOG);
    float feat[65];
    #pragma unroll
    for (int k=0;k<5;k++) feat[k]=xd[k];
    #pragma unroll
    for (int j=0;j<5;j++){
        float mean = sum[j]/cc, msq = ssq[j]/cc;
        float sd = sqrtf(fmaxf(msq - mean*mean, 0.f) + 1e-5f);
        feat[5+j]=mean;
        feat[10+j]= (deg>0)? mn[j] : 0.f;
        feat[15+j]= (deg>0)? mx[j] : 0.f;
        feat[20+j]=sd;
    }
    #pragma unroll
    for (int j=0;j<20;j++){ feat[25+j]=feat[5+j]*amp; feat[45+j]=feat[5+j]/amp; }
    float t = sbpost[g];
    #pragma unroll
    for (int k=0;k<65;k++) t += feat[k]*sWpost[k*8+g];
    float nf = sbpna[g];
    #pragma unroll
    for (int k=0;k<8;k++) nf += __shfl(t, k, 8) * sWpna[k*8+g];
    float nfk[8];
    #pragma unroll
    for (int k=0;k<8;k++) nfk[k] = __shfl(nf, k, 8);
    #pragma unroll
    for (int u=0;u<2;u++){
        int o = 2*g+u;
        float a=sb1l[o], b2=sb1r[o];
        #pragma unroll
        for (int k=0;k<8;k++){ a += nfk[k]*sW1l[k*16+o]; b2 += nfk[k]*sW1r[k*16+o]; }
        xl1[node*16+o]=a; xr1[node*16+o]=b2;
    }
    if (g==0) ea_mean[node] = wsum/cc;
}

// ================= GAT layer 1 gather (online softmax, self-loop virtual edge) =================
__global__ __launch_bounds__(256) void k_gat1(
    const int* __restrict__ cnt_d, const int* __restrict__ off_d,
    const int* __restrict__ adjC,
    const float* __restrict__ xl1, const float* __restrict__ xr1,
    const float* __restrict__ ea_mean,
    const float* __restrict__ We1, const float* __restrict__ att1, const float* __restrict__ bias1,
    const float* __restrict__ W2l, const float* __restrict__ b2l,
    const float* __restrict__ W2r, const float* __restrict__ b2r,
    _Float16* __restrict__ xl2h, float* __restrict__ xr2)
{
    __shared__ float sWe[16], sAtt[16], sBias[16], sW2l[512], sW2r[512], sb2l[32], sb2r[32];
    for (int t=threadIdx.x; t<512; t+=256){ sW2l[t]=W2l[t]; sW2r[t]=W2r[t]; }
    if (threadIdx.x<16){ sWe[threadIdx.x]=We1[threadIdx.x]; sAtt[threadIdx.x]=att1[threadIdx.x]; sBias[threadIdx.x]=bias1[threadIdx.x]; }
    if (threadIdx.x<32){ sb2l[threadIdx.x]=b2l[threadIdx.x]; sb2r[threadIdx.x]=b2r[threadIdx.x]; }
    __syncthreads();
    int node = blockIdx.x*32 + (threadIdx.x>>3);
    if (node >= NN) return;
    int g = threadIdx.x & 7;
    float xr[16];
    #pragma unroll
    for (int k=0;k<4;k++){
        float4 v = *(const float4*)(xr1 + node*16 + k*4);
        xr[k*4]=v.x; xr[k*4+1]=v.y; xr[k*4+2]=v.z; xr[k*4+3]=v.w;
    }
    int deg = cnt_d[node], base = off_d[node];
    float eam = ea_mean[node];
    float m[4], ss[4], acc[16];
    #pragma unroll
    for (int h=0;h<4;h++){ m[h]=-1e30f; ss[h]=0.f; }
    #pragma unroll
    for (int k=0;k<16;k++) acc[k]=0.f;
    for (int j=g; j<=deg; j+=8){
        bool selfe = (j==deg);
        int s; float w;
        if (selfe){ s = node; w = eam; }
        else { int ent = adjC[base+j]; s = cent_node(ent); w = cent_w(ent); }
        float xls[16];
        #pragma unroll
        for (int k=0;k<4;k++){
            float4 v = *(const float4*)(xl1 + s*16 + k*4);
            xls[k*4]=v.x; xls[k*4+1]=v.y; xls[k*4+2]=v.z; xls[k*4+3]=v.w;
        }
        #pragma unroll
        for (int h=0;h<4;h++){
            float a = 0.f;
            #pragma unroll
            for (int ch=0;ch<4;ch++){
                int idx = h*4+ch;
                a += lrelu(xls[idx] + xr[idx] + w*sWe[idx]) * sAtt[idx];
            }
            float mn2 = fmaxf(m[h], a);
            float corr = __expf(m[h]-mn2);
            float p = __expf(a-mn2);
            ss[h] = ss[h]*corr + p;
            #pragma unroll
            for (int ch=0;ch<4;ch++){
                int idx = h*4+ch;
                acc[idx] = acc[idx]*corr + p*xls[idx];
            }
            m[h] = mn2;
        }
    }
    #pragma unroll
    for (int st=1; st<8; st<<=1){
        #pragma unroll
        for (int h=0;h<4;h++){
            float mo = __shfl_xor(m[h], st);
            float so = __shfl_xor(ss[h], st);
            float mn2 = fmaxf(m[h], mo);
            float ca = __expf(m[h]-mn2), cbb = __expf(mo-mn2);
            ss[h] = ss[h]*ca + so*cbb;
            #pragma unroll
            for (int ch=0;ch<4;ch++){
                int idx=h*4+ch;
                float ao = __shfl_xor(acc[idx], st);
                acc[idx] = acc[idx]*ca + ao*cbb;
            }
            m[h]=mn2;
        }
    }
    float nf1[16];
    #pragma unroll
    for (int h=0;h<4;h++){
        float den = ss[h] + 1e-16f;
        #pragma unroll
        for (int ch=0;ch<4;ch++){
            int idx=h*4+ch;
            nf1[idx] = relu(acc[idx]/den + sBias[idx]);
        }
    }
    #pragma unroll
    for (int u=0;u<4;u++){
        int o = g + 8*u;
        float a=sb2l[o], b=sb2r[o];
        #pragma unroll
        for (int k=0;k<16;k++){ a += nf1[k]*sW2l[k*32+o]; b += nf1[k]*sW2r[k*32+o]; }
        xl2h[(size_t)node*32+o] = (_Float16)a;
        xr2[node*32+o]=b;
    }
}

// ================= GAT layer 2 gather + Wn MLP + We_fc projections =================
__global__ __launch_bounds__(256) void k_gat2(
    const int* __restrict__ cnt_d, const int* __restrict__ off_d,
    const int* __restrict__ adjC,
    const _Float16* __restrict__ xl2h, const float* __restrict__ xr2,
    const float* __restrict__ ea_mean,
    const float* __restrict__ We2, const float* __restrict__ att2, const float* __restrict__ bias2,
    const float* __restrict__ Wn, const float* __restrict__ bn,
    const float* __restrict__ We_fc,
    _Float16* __restrict__ Ps16, _Float16* __restrict__ Pd16,
    float* __restrict__ Ps01, float* __restrict__ Pd01)
{
    __shared__ float sWe[32], sAtt[32], sBias[32], sWn[1024], sbn[32];
    __shared__ float sWsrc[1024], sWdst[1024];
    for (int t=threadIdx.x; t<1024; t+=256){
        sWn[t]=Wn[t];
        sWsrc[t]=We_fc[32 + t];
        sWdst[t]=We_fc[33*32 + t];
    }
    if (threadIdx.x<32){ sWe[threadIdx.x]=We2[threadIdx.x]; sAtt[threadIdx.x]=att2[threadIdx.x];
                         sBias[threadIdx.x]=bias2[threadIdx.x]; sbn[threadIdx.x]=bn[threadIdx.x]; }
    __syncthreads();
    int node = blockIdx.x*32 + (threadIdx.x>>3);
    if (node >= NN) return;
    int g = threadIdx.x & 7;
    float xr[32];
    #pragma unroll
    for (int k=0;k<8;k++){
        float4 v = *(const float4*)(xr2 + node*32 + k*4);
        xr[k*4]=v.x; xr[k*4+1]=v.y; xr[k*4+2]=v.z; xr[k*4+3]=v.w;
    }
    int deg = cnt_d[node], base = off_d[node];
    float eam = ea_mean[node];
    float m[4], ss[4], acc[32];
    #pragma unroll
    for (int h=0;h<4;h++){ m[h]=-1e30f; ss[h]=0.f; }
    #pragma unroll
    for (int k=0;k<32;k++) acc[k]=0.f;
    for (int j=g; j<=deg; j+=8){
        bool selfe = (j==deg);
        int s; float w;
        if (selfe){ s = node; w = eam; }
        else { int ent = adjC[base+j]; s = cent_node(ent); w = cent_w(ent); }
        float xls[32];
        const h8v* xp = (const h8v*)(xl2h + (size_t)s*32);
        #pragma unroll
        for (int k=0;k<4;k++){
            h8v hv = xp[k];
            #pragma unroll
            for (int u=0;u<8;u++) xls[k*8+u] = (float)hv[u];
        }
        #pragma unroll
        for (int h=0;h<4;h++){
            float a = 0.f;
            #pragma unroll
            for (int ch=0;ch<8;ch++){
                int idx = h*8+ch;
                a += lrelu(xls[idx] + xr[idx] + w*sWe[idx]) * sAtt[idx];
            }
            float mn2 = fmaxf(m[h], a);
            float corr = __expf(m[h]-mn2);
            float p = __expf(a-mn2);
            ss[h] = ss[h]*corr + p;
            #pragma unroll
            for (int ch=0;ch<8;ch++){
                int idx = h*8+ch;
                acc[idx] = acc[idx]*corr + p*xls[idx];
            }
            m[h] = mn2;
        }
    }
    #pragma unroll
    for (int st=1; st<8; st<<=1){
        #pragma unroll
        for (int h=0;h<4;h++){
            float mo = __shfl_xor(m[h], st);
            float so = __shfl_xor(ss[h], st);
            float mn2 = fmaxf(m[h], mo);
            float ca = __expf(m[h]-mn2), cbb = __expf(mo-mn2);
            ss[h] = ss[h]*ca + so*cbb;
            #pragma unroll
            for (int ch=0;ch<8;ch++){
                int idx=h*8+ch;
                float ao = __shfl_xor(acc[idx], st);
                acc[idx] = acc[idx]*ca + ao*cbb;
            }
            m[h]=mn2;
        }
    }
    float nf2[32];
    #pragma unroll
    for (int h=0;h<4;h++){
        float den = ss[h] + 1e-16f;
        #pragma unroll
        for (int ch=0;ch<8;ch++){
            int idx=h*8+ch;
            nf2[idx] = relu(acc[idx]/den + sBias[idx]);
        }
    }
    float mine[4];
    #pragma unroll
    for (int u=0;u<4;u++){
        int oo = g + 8*u;
        float a = sbn[oo];
        #pragma unroll
        for (int k=0;k<32;k++) a += nf2[k]*sWn[k*32+oo];
        mine[u] = relu(a);
    }
    float nfn[32];
    #pragma unroll
    for (int k=0;k<32;k++) nfn[k] = __shfl(mine[k>>3], k&7, 8);
    float pa[4], pb[4];
    #pragma unroll
    for (int u=0;u<4;u++){
        int oo = g + 8*u;
        float a=0.f, b=0.f;
        #pragma unroll
        for (int k=0;k<32;k++){ a += nfn[k]*sWsrc[k*32+oo]; b += nfn[k]*sWdst[k*32+oo]; }
        pa[u]=a; pb[u]=b;
        Ps16[(size_t)node*32+oo] = (_Float16)a;
        Pd16[(size_t)node*32+oo] = (_Float16)b;
    }
    float ps0=__shfl(pa[0],0,8), ps1=__shfl(pa[0],1,8);
    float pd0=__shfl(pb[0],0,8), pd1=__shfl(pb[0],1,8);
    if (g==0){
        *(float2*)(Ps01 + node*2) = make_float2(ps0, ps1);
        *(float2*)(Pd01 + node*2) = make_float2(pd0, pd1);
    }
}

// ================= per-src softmax stats from COARSE src buffer (single read) =================
__global__ __launch_bounds__(1024) void k_src_bins(
    const int2* __restrict__ cS, const int* __restrict__ binStartS,
    const float* __restrict__ Ps01, const float* __restrict__ Pd01,
    const float* __restrict__ We_fc, const float* __restrict__ be_fc,
    float4* __restrict__ ssd)
{
    __shared__ float sPs0[256], sPs1[256];
    __shared__ unsigned sM0[256], sM1[256];
    __shared__ float sS0[256], sS1[256];
    __shared__ float cW00, cW01, cbe0, cbe1;
    int bin = blockIdx.x, tid = threadIdx.x;
    if (tid == 0){ cW00=We_fc[0]; cW01=We_fc[1]; cbe0=be_fc[0]; cbe1=be_fc[1]; }
    if (tid < 256){
        int node = (bin<<8) + tid;
        float2 p = (node < NN) ? *(const float2*)(Ps01 + node*2) : make_float2(0.f,0.f);
        sPs0[tid]=p.x; sPs1[tid]=p.y;
        sM0[tid]=fenc(-1e30f); sM1[tid]=fenc(-1e30f);
        sS0[tid]=0.f; sS1[tid]=0.f;
    }
    __syncthreads();
    int S = binStartS[bin], E = binStartS[bin+1];
    const int REG = 9;
    float ra0[REG], ra1[REG]; int rl[REG];
    int n = 0;
    {
        int idx = S + tid;
        #pragma unroll
        for (int it = 0; it < REG; ++it){
            if (idx < E){
                int2 ent = cS[idx];
                unsigned y = (unsigned)ent.y;
                int local = y >> 24;
                int d = ent.x;
                float w = ((float)(y & 0x7FFFFu) + 0.5f) * (1.0f/524288.0f);
                float2 q = *(const float2*)(Pd01 + d*2);
                float a0 = cbe0 + sPs0[local] + w*cW00 + q.x;
                float a1 = cbe1 + sPs1[local] + w*cW01 + q.y;
                ra0[it]=a0; ra1[it]=a1; rl[it]=local; n = it+1;
                atomicMax(&sM0[local], fenc(a0));
                atomicMax(&sM1[local], fenc(a1));
            }
            idx += 1024;
        }
        for (int i = S + tid + REG*1024; i < E; i += 1024){
            int2 ent = cS[i];
            unsigned y = (unsigned)ent.y;
            int local = y >> 24;
            int d = ent.x;
            float w = ((float)(y & 0x7FFFFu) + 0.5f) * (1.0f/524288.0f);
            float2 q = *(const float2*)(Pd01 + d*2);
            atomicMax(&sM0[local], fenc(cbe0 + sPs0[local] + w*cW00 + q.x));
            atomicMax(&sM1[local], fenc(cbe1 + sPs1[local] + w*cW01 + q.y));
        }
    }
    __syncthreads();
    #pragma unroll
    for (int it = 0; it < REG; ++it){
        if (it < n){
            atomicAdd(&sS0[rl[it]], __expf(ra0[it] - fdec(sM0[rl[it]])));
            atomicAdd(&sS1[rl[it]], __expf(ra1[it] - fdec(sM1[rl[it]])));
        }
    }
    for (int i = S + tid + REG*1024; i < E; i += 1024){
        int2 ent = cS[i];
        unsigned y = (unsigned)ent.y;
        int local = y >> 24;
        int d = ent.x;
        float w = ((float)(y & 0x7FFFFu) + 0.5f) * (1.0f/524288.0f);
        float2 q = *(const float2*)(Pd01 + d*2);
        atomicAdd(&sS0[local], __expf(cbe0 + sPs0[local] + w*cW00 + q.x - fdec(sM0[local])));
        atomicAdd(&sS1[local], __expf(cbe1 + sPs1[local] + w*cW01 + q.y - fdec(sM1[local])));
    }
    __syncthreads();
    if (tid < 256){
        int node = (bin<<8) + tid;
        if (node < NN) ssd[node] = make_float4(fdec(sM0[tid]), fdec(sM1[tid]), sS0[tid], sS1[tid]);
    }
}

// ================= per-src softmax stats (fallback: compact 4B entries) =================
__global__ __launch_bounds__(256) void k_src(
    const int* __restrict__ cnt_s, const int* __restrict__ off_s,
    const int* __restrict__ bkts,
    const float* __restrict__ Ps01, const float* __restrict__ Pd01,
    const float* __restrict__ We_fc, const float* __restrict__ be_fc,
    float4* __restrict__ ssd)
{
    __shared__ float sW00, sW01, sbe0, sbe1;
    if (threadIdx.x == 0){ sW00=We_fc[0]; sW01=We_fc[1]; sbe0=be_fc[0]; sbe1=be_fc[1]; }
    __syncthreads();
    int node = blockIdx.x*32 + (threadIdx.x>>3);
    if (node >= NN) return;
    int g = threadIdx.x & 7;
    float2 p = *(const float2*)(Ps01 + node*2);
    float base0 = sbe0 + p.x, base1 = sbe1 + p.y;
    int deg = cnt_s[node], base = off_s[node];
    float m0=-1e30f, m1=-1e30f, s0=0.f, s1=0.f;
    for (int j=g; j<deg; j+=8){
        int ent = bkts[base+j];
        int d = cent_node(ent);
        float w = cent_w(ent);
        float2 q = *(const float2*)(Pd01 + d*2);
        float a0 = base0 + w*sW00 + q.x;
        float a1 = base1 + w*sW01 + q.y;
        float mn0 = fmaxf(m0, a0);
        s0 = s0*__expf(m0-mn0) + __expf(a0-mn0); m0 = mn0;
        float mn1 = fmaxf(m1, a1);
        s1 = s1*__expf(m1-mn1) + __expf(a1-mn1); m1 = mn1;
    }
    #pragma unroll
    for (int st=1; st<8; st<<=1){
        float mo = __shfl_xor(m0, st), so = __shfl_xor(s0, st);
        float mn = fmaxf(m0, mo);
        s0 = s0*__expf(m0-mn) + so*__expf(mo-mn); m0 = mn;
        mo = __shfl_xor(m1, st); so = __shfl_xor(s1, st);
        mn = fmaxf(m1, mo);
        s1 = s1*__expf(m1-mn) + so*__expf(mo-mn); m1 = mn;
    }
    if (g==0) ssd[node] = make_float4(m0, m1, s0, s1);
}

// ================= final edge scores (eid-ordered, octet-per-edge: full-line writes) =================
__global__ __launch_bounds__(256) void k_scF2(
    const int* __restrict__ src, const int* __restrict__ dst, const float* __restrict__ ea,
    const _Float16* __restrict__ Ps16, const _Float16* __restrict__ Pd16,
    const float* __restrict__ We_fc, const float* __restrict__ be_fc,
    const float4* __restrict__ ssd,
    float* __restrict__ out)
{
    __shared__ float sW0[32], sB[32];
    if (threadIdx.x < 32){ sW0[threadIdx.x]=We_fc[threadIdx.x]; sB[threadIdx.x]=be_fc[threadIdx.x]; }
    __syncthreads();
    int e = blockIdx.x*32 + (threadIdx.x>>3);
    if (e >= NE) return;
    int g = threadIdx.x & 7;
    int s = src[e], d = dst[e];
    float w = ea[e];
    h4v a = *(const h4v*)(Ps16 + (size_t)s*32 + g*4);
    h4v b = *(const h4v*)(Pd16 + (size_t)d*32 + g*4);
    float4 w0 = *(const float4*)(sW0 + g*4);
    float4 b0 = *(const float4*)(sB + g*4);
    float ox = b0.x + w*w0.x + (float)a.x + (float)b.x;
    float oy = b0.y + w*w0.y + (float)a.y + (float)b.y;
    float oz = b0.z + w*w0.z + (float)a.z + (float)b.z;
    float ow = b0.w + w*w0.w + (float)a.w + (float)b.w;
    if (g == 0){
        float4 v = ssd[s];
        ox = __expf(ox - v.x) / (v.z + 1e-16f);
        oy = __expf(oy - v.y) / (v.w + 1e-16f);
    }
    f4v ov; ov.x=ox; ov.y=oy; ov.z=oz; ov.w=ow;
    __builtin_nontemporal_store(ov, (f4v*)(out + (size_t)e*32 + g*4));
}

extern "C" void kernel_launch(void* const* d_in, const int* in_sizes, int n_in,
                              void* d_out, int out_size, void* d_ws, size_t ws_size,
                              hipStream_t stream) {
    const float* x     = (const float*)d_in[0];
    const int*   ei    = (const int*)  d_in[1];
    const float* ea    = (const float*)d_in[2];
    const float* W_ee  = (const float*)d_in[3];  const float* b_ee  = (const float*)d_in[4];
    const float* W_pre = (const float*)d_in[5];  const float* b_pre = (const float*)d_in[6];
    const float* W_post= (const float*)d_in[7];  const float* b_post= (const float*)d_in[8];
    const float* W_pna = (const float*)d_in[9];  const float* b_pna = (const float*)d_in[10];
    const float* W1l   = (const float*)d_in[11]; const float* b1l   = (const float*)d_in[12];
    const float* W1r   = (const float*)d_in[13]; const float* b1r   = (const float*)d_in[14];
    const float* W1e   = (const float*)d_in[15]; const float* att1  = (const float*)d_in[16];
    const float* bias1 = (const float*)d_in[17];
    const float* W2l   = (const float*)d_in[18]; const float* b2l   = (const float*)d_in[19];
    const float* W2r   = (const float*)d_in[20]; const float* b2r   = (const float*)d_in[21];
    const float* W2e   = (const float*)d_in[22]; const float* att2  = (const float*)d_in[23];
    const float* bias2 = (const float*)d_in[24];
    const float* Wn    = (const float*)d_in[25]; const float* bn    = (const float*)d_in[26];
    const float* We_fc = (const float*)d_in[27]; const float* be_fc = (const float*)d_in[28];
    const int* src = ei;
    const int* dst = ei + NE;
    float* out = (float*)d_out;

    float* ws = (float*)d_ws;
    size_t o = 0;
    auto A = [&](size_t n){ size_t r = o; o = (o + n + 63) & ~(size_t)63; return r; };
    int*   cnt_d  = (int*)(ws + A(NN));
    int*   off_d  = (int*)(ws + A(NN));
    int*   cnt_s  = (int*)(ws + A(NN));
    int*   off_s  = (int*)(ws + A(NN));
    int*   cur_d  = (int*)(ws + A(NN));
    int*   cur_s  = (int*)(ws + A(NN));
    float* xl1    =        ws + A((size_t)NN*16);
    float* xr1    =        ws + A((size_t)NN*16);
    _Float16* xl2h = (_Float16*)(ws + A((size_t)NN*16));   // NN*32 halfs
    float* xr2    =        ws + A((size_t)NN*32);
    _Float16* Ps16 = (_Float16*)(ws + A((size_t)NN*16));   // NN*32 halfs
    _Float16* Pd16 = (_Float16*)(ws + A((size_t)NN*16));   // NN*32 halfs
    float* ea_mean=        ws + A(NN);
    float* Ps01   =        ws + A((size_t)NN*2);
    float* Pd01   =        ws + A((size_t)NN*2);
    float4* ssd   = (float4*)(ws + A((size_t)NN*4));
    int*   histD  = (int*)(ws + A((size_t)NBIN*NCHUNK));
    int*   histS  = (int*)(ws + A((size_t)NBIN*NCHUNK));
    int*   baseD  = (int*)(ws + A((size_t)NBIN*NCHUNK));
    int*   baseS  = (int*)(ws + A((size_t)NBIN*NCHUNK));
    int*   binTotal  = (int*)(ws + A(2*NBIN));
    int*   binStartD = (int*)(ws + A(NBIN+1));
    int*   binStartS = (int*)(ws + A(NBIN+1));
    int*   adjC  = (int*)(ws + A((size_t)NE));     // dst adjacency (4B compact)
    int*   bktsC = (int*)(ws + A((size_t)NE));     // fallback src adjacency (4B)
    size_t o_fallback = o;
    int2*  bufY = (int2*)(ws + A(2*(size_t)NE));   // coarse dst
    int2*  bufZ = (int2*)(ws + A(2*(size_t)NE));   // coarse src (persists to k_src_bins)
    size_t o_sort = o;
    bool sortmode = (ws_size >= o_sort * sizeof(float));
    if (!sortmode && ws_size < o_fallback * sizeof(float)) return;  // fail loudly

    const int BS = 256;
    const int gridE = (NE + BS - 1)/BS;
    const int gridN = (NN + BS - 1)/BS;
    const int gridO = (NN + 31)/32;
    const int gridF = (NE + 31)/32;

    if (sortmode){
        k_hist<<<NCHUNK, BS, 0, stream>>>(src, dst, histD, histS);
        k_binsum<<<2*NBIN, BS, 0, stream>>>(histD, histS, binTotal);
        k_chunkpfx<<<2*NBIN, BS, 0, stream>>>(histD, histS, binTotal, binStartD, binStartS, baseD, baseS);
        k_coarse<<<NCHUNK, BS, 0, stream>>>(src, dst, ea, baseD, baseS, bufY, bufZ);
        k_fine<<<NBIN, BS, 0, stream>>>(bufY, binStartD, adjC, cnt_d, off_d);
    } else {
        k_zero<<<gridN, BS, 0, stream>>>(cnt_d, cnt_s);
        k_count<<<gridE, BS, 0, stream>>>(src, dst, cnt_d, cnt_s);
        k_scanCSR<<<2, 1024, 0, stream>>>(cnt_d, cnt_s, off_d, cur_d, off_s, cur_s);
        k_scatter<<<gridE, BS, 0, stream>>>(src, dst, ea, cur_d, cur_s, adjC, bktsC);
    }
    k_pna<<<gridO, BS, 0, stream>>>(x, cnt_d, off_d, adjC,
                                    W_ee, b_ee, W_pre, b_pre, W_post, b_post, W_pna, b_pna,
                                    W1l, b1l, W1r, b1r, xl1, xr1, ea_mean);
    k_gat1<<<gridO, BS, 0, stream>>>(cnt_d, off_d, adjC, xl1, xr1, ea_mean,
                                     W1e, att1, bias1, W2l, b2l, W2r, b2r, xl2h, xr2);
    k_gat2<<<gridO, BS, 0, stream>>>(cnt_d, off_d, adjC, xl2h, xr2, ea_mean,
                                     W2e, att2, bias2, Wn, bn, We_fc,
                                     Ps16, Pd16, Ps01, Pd01);
    if (sortmode){
        k_src_bins<<<NBIN, 1024, 0, stream>>>(bufZ, binStartS, Ps01, Pd01, We_fc, be_fc, ssd);
    } else {
        k_src<<<gridO, BS, 0, stream>>>(cnt_s, off_s, bktsC, Ps01, Pd01, We_fc, be_fc, ssd);
    }
    k_scF2<<<gridF, BS, 0, stream>>>(src, dst, ea, Ps16, Pd16, We_fc, be_fc, ssd, out);
}